// Round 7
// baseline (284.348 us; speedup 1.0000x reference)
//
#include <hip/hip_runtime.h>
#include <hip/hip_bf16.h>
#include <stdint.h>

#define TT   65536
#define NCH  16
#define CNOM 16
#define NBLK 256
#define ROWB 1664            // bytes per packed igate row (6*256 used + 128 pad)

typedef __bf16 bf16x8 __attribute__((ext_vector_type(8)));
typedef float  f32x4  __attribute__((ext_vector_type(4)));
typedef int    i32x4  __attribute__((ext_vector_type(4)));

__device__ __bf16 g_whh[768 * 256];
__device__ __align__(64) unsigned char g_ig[(size_t)TT * ROWB];

__device__ __forceinline__ float bfbits(uint32_t u) {
  float f; __builtin_memcpy(&f, &u, 4); return f;
}

// asm MFMA wrappers (scan only). *_0: inline-constant-0 srcC, "=&v" early-clobber.
__device__ __forceinline__ void mfma_bv0(f32x4& acc, bf16x8 a, i32x4 b) {
  asm("v_mfma_f32_16x16x32_bf16 %0, %1, %2, 0" : "=&v"(acc) : "v"(a), "v"(b));
}
__device__ __forceinline__ void mfma_ba0(f32x4& acc, bf16x8 a, i32x4 b) {
  asm("v_mfma_f32_16x16x32_bf16 %0, %1, %2, 0" : "=&v"(acc) : "v"(a), "a"(b));
}
__device__ __forceinline__ void mfma_bv(f32x4& acc, bf16x8 a, i32x4 b) {
  asm("v_mfma_f32_16x16x32_bf16 %0, %1, %2, %0" : "+v"(acc) : "v"(a), "v"(b));
}
__device__ __forceinline__ void mfma_ba(f32x4& acc, bf16x8 a, i32x4 b) {
  asm("v_mfma_f32_16x16x32_bf16 %0, %1, %2, %0" : "+v"(acc) : "v"(a), "a"(b));
}

__device__ __forceinline__ bf16x8 cvt8v(f32x4 f0, f32x4 f1) {
  bf16x8 v;
  v[0] = (__bf16)f0[0]; v[1] = (__bf16)f0[1]; v[2] = (__bf16)f0[2]; v[3] = (__bf16)f0[3];
  v[4] = (__bf16)f1[0]; v[5] = (__bf16)f1[1]; v[6] = (__bf16)f1[2]; v[7] = (__bf16)f1[3];
  return v;
}

// phase 1: igates = x @ W_ih^T + bias -> packed rows; also converts whh->bf16
// (prep_w folded in). 1024 blocks x 256 thr: 64-row m-tile, all 6 n-tiles
// in-block, 64 KB LDS -> TWO blocks/CU. One block's W-panel load latency hides
// under the other block's compute (R6's 1-block/CU exposed ~500 cyc per ci).
// x loads nontemporal (read-once; keep L3 for g_ig).
__global__ __launch_bounds__(256) void gemm_ig(const float* __restrict__ x,
                                               const float* __restrict__ wih,
                                               const float* __restrict__ whh,
                                               const float* __restrict__ bias) {
  __shared__ __align__(16) __bf16 a_s[4][64 * 64];    // 32 KB: x tile, kc-chunked
  __shared__ __align__(16) __bf16 b_s[2][128 * 64];   // 32 KB: W panel dbuf
  const int tid = threadIdx.x;
  const int lane = tid & 63, l15 = lane & 15, q = lane >> 4;
  const int w = tid >> 6;                             // wave = 32 cols per ntb
  const int m0 = blockIdx.x * 64;

  // prep_w fold: blocks 0..767 convert whh (768*256 elems, 1/thread)
  {
    int i = blockIdx.x * 256 + tid;
    if (i < 768 * 256) g_whh[i] = (__bf16)whh[i];
  }

  float bvA[6], bvB[6];
#pragma unroll
  for (int nb = 0; nb < 6; ++nb) {
    bvA[nb] = bias[nb * 128 + w * 32 + l15];
    bvB[nb] = bias[nb * 128 + w * 32 + 16 + l15];
  }

  // stage x once: LDS[row][c] = global chunk c^(row&7) (write-side swizzle)
#pragma unroll
  for (int kc = 0; kc < 4; ++kc)
#pragma unroll
    for (int i = 0; i < 2; ++i) {
      int pslot = i * 256 + tid;
      int row = pslot >> 3, c = pslot & 7, cs = c ^ (row & 7);
      const f32x4* xs = (const f32x4*)(x + (size_t)(m0 + row) * 256 + kc * 64 + cs * 8);
      f32x4 f0 = __builtin_nontemporal_load(xs);
      f32x4 f1 = __builtin_nontemporal_load(xs + 1);
      *(bf16x8*)((char*)a_s[kc] + pslot * 16) = cvt8v(f0, f1);
    }
  // prologue: W(ntb=0,kc=0) -> b_s[0]
#pragma unroll
  for (int it = 0; it < 4; ++it) {
    int pslot = it * 256 + tid;
    int row = pslot >> 3, c = pslot & 7, cs = c ^ (row & 7);
    const f32x4* ws = (const f32x4*)(wih + (size_t)row * 256 + cs * 8);
    *(bf16x8*)((char*)b_s[0] + pslot * 16) = cvt8v(ws[0], ws[1]);
  }

  f32x4 acc[4][2];
#pragma unroll
  for (int a = 0; a < 4; ++a)
#pragma unroll
    for (int b = 0; b < 2; ++b) acc[a][b] = (f32x4){0.f, 0.f, 0.f, 0.f};
  __syncthreads();

  for (int ci = 0; ci < 24; ++ci) {
    const int ntb = ci >> 2, kc = ci & 3, buf = ci & 1;
    const int nn = (ci + 1) >> 2, kk = (ci + 1) & 3;
    const bool more = (ci + 1) < 24;
    f32x4 wf0[4], wf1[4];
    if (more) {   // issue next W panel loads early (hidden under MFMA + 2nd block)
#pragma unroll
      for (int it = 0; it < 4; ++it) {
        int pslot = it * 256 + tid;
        int row = pslot >> 3, c = pslot & 7, cs = c ^ (row & 7);
        const f32x4* ws = (const f32x4*)(wih + (size_t)(nn * 128 + row) * 256 + kk * 64 + cs * 8);
        wf0[it] = ws[0]; wf1[it] = ws[1];
      }
    }
#pragma unroll
    for (int ks = 0; ks < 2; ++ks) {
      bf16x8 af[4], bfr[2];
#pragma unroll
      for (int tm = 0; tm < 4; ++tm) {
        int row = tm * 16 + l15;
        int cb = (ks * 4 + q) ^ (row & 7);
        af[tm] = *(const bf16x8*)((const char*)a_s[kc] + row * 128 + cb * 16);
      }
#pragma unroll
      for (int tn = 0; tn < 2; ++tn) {
        int row = w * 32 + tn * 16 + l15;
        int cb = (ks * 4 + q) ^ (row & 7);
        bfr[tn] = *(const bf16x8*)((const char*)b_s[buf] + row * 128 + cb * 16);
      }
#pragma unroll
      for (int tm = 0; tm < 4; ++tm)
#pragma unroll
        for (int tn = 0; tn < 2; ++tn)
          acc[tm][tn] = __builtin_amdgcn_mfma_f32_16x16x32_bf16(af[tm], bfr[tn], acc[tm][tn], 0, 0, 0);
    }
    if (more) {   // write next W panel into the idle buffer
#pragma unroll
      for (int it = 0; it < 4; ++it)
        *(bf16x8*)((char*)b_s[buf ^ 1] + (it * 256 + tid) * 16) = cvt8v(wf0[it], wf1[it]);
    }
    if (kc == 3) {
#pragma unroll
      for (int tm = 0; tm < 4; ++tm)
#pragma unroll
        for (int r = 0; r < 4; ++r) {
          int t = m0 + tm * 16 + q * 4 + r;
          __bf16 lo = (__bf16)(acc[tm][0][r] + bvA[ntb]);
          __bf16 hi = (__bf16)(acc[tm][1][r] + bvB[ntb]);
          unsigned short ulo, uhi;
          __builtin_memcpy(&ulo, &lo, 2); __builtin_memcpy(&uhi, &hi, 2);
          uint32_t u = (uint32_t)ulo | ((uint32_t)uhi << 16);
          *(uint32_t*)(g_ig + (size_t)t * ROWB + ntb * 256 + w * 64 + l15 * 4) = u;
        }
#pragma unroll
      for (int a = 0; a < 4; ++a)
#pragma unroll
        for (int b = 0; b < 2; ++b) acc[a][b] = (f32x4){0.f, 0.f, 0.f, 0.f};
    }
    __syncthreads();
  }
}

// phase 2: the scan — structure unchanged from R6 (passing). Changes:
// out stores nontemporal (write-once; keeps g_ig L3-resident -> lower FETCH
// and lower ig-load latency), fin_copy folded (t==TT-1 writes final-state row).
__global__ __launch_bounds__(512)
__attribute__((amdgpu_waves_per_eu(2, 2)))
void gru_scan(const float* __restrict__ state, const int* __restrict__ start,
              const float* __restrict__ bias_n, float* __restrict__ out) {
  __shared__ __align__(16) __bf16 h_s[2][16][264];
  __shared__ __align__(16) unsigned char whh_lds[8 * 16 * 1024];
  __shared__ int flg_s[16 * 132];
  __shared__ int s_arr[17];

  const int tid = threadIdx.x;
  const int w = tid >> 6, lane = tid & 63, l15 = lane & 15, q = lane >> 4;
  const int jrow0 = w * 32 + l15;

  if (tid < 17) {
    int t = (blockIdx.x * NCH + tid) * CNOM;
    if (t > 0) { while (t < TT && start[t] == 0) t++; }
    s_arr[tid] = t;
  }
  for (int i = tid; i < 16 * 264; i += 512) (&h_s[0][0][0])[i] = (__bf16)0.f;
  __syncthreads();

  int sa[4], len[4];
#pragma unroll
  for (int r = 0; r < 4; ++r) {
    sa[r] = s_arr[q * 4 + r];
    len[r] = s_arr[q * 4 + r + 1] - sa[r];
  }
  int ML = 0;
  for (int m = 0; m < 16; ++m) { int L = s_arr[m + 1] - s_arr[m]; ML = L > ML ? L : ML; }
  ML = __builtin_amdgcn_readfirstlane(ML);

  for (int idx = tid; idx < 2048; idx += 512) {
    int m = idx >> 7, kk = idx & 127;
    int t = s_arr[m] + kk;
    flg_s[m * 132 + kk] = (t < TT) ? start[t] : 0;
  }

  // W_hh c=0 (r-gate) -> per-wave LDS
  char* lp = (char*)whh_lds + w * 16384 + lane * 16;
#pragma unroll
  for (int p = 0; p < 2; ++p)
#pragma unroll
    for (int ks = 0; ks < 8; ++ks) {
      i32x4 t = *(const i32x4*)&g_whh[(size_t)(w * 32 + p * 16 + l15) * 256 + q * 8 + ks * 32];
      *(i32x4*)(lp + (p * 8 + ks) * 1024) = t;
    }
  // W_hh c=1 (z), c=2 (n) -> AGPRs
  i32x4 whh_z[2][8], whh_n[2][8];
#pragma unroll
  for (int p = 0; p < 2; ++p)
#pragma unroll
    for (int ks = 0; ks < 8; ++ks) {
      whh_z[p][ks] = *(const i32x4*)&g_whh[(size_t)(1 * 256 + w * 32 + p * 16 + l15) * 256 + q * 8 + ks * 32];
      whh_n[p][ks] = *(const i32x4*)&g_whh[(size_t)(2 * 256 + w * 32 + p * 16 + l15) * 256 + q * 8 + ks * 32];
    }
#pragma unroll
  for (int p = 0; p < 2; ++p)
#pragma unroll
    for (int ks = 0; ks < 8; ++ks) {
      asm volatile("" : "+a"(whh_z[p][ks]));
      asm volatile("" : "+a"(whh_n[p][ks]));
    }

  const float bn2[2] = { bias_n[jrow0], bias_n[jrow0 + 16] };

  const int start0 = start[0];
  if (blockIdx.x == 0 && tid < 256) h_s[0][0][tid] = start0 ? (__bf16)0.f : (__bf16)state[tid];

  float hreg[2][4];
#pragma unroll
  for (int p = 0; p < 2; ++p)
#pragma unroll
    for (int r = 0; r < 4; ++r) hreg[p][r] = 0.f;
  if (blockIdx.x == 0 && q == 0 && !start0) {
    hreg[0][0] = state[jrow0];
    hreg[1][0] = state[jrow0 + 16];
  }

  const int cw = (w >> 2) * 256 + ((w & 3) * 16 + l15) * 4;
  const uint32_t offlim = (uint32_t)(TT - 1) * ROWB + (uint32_t)cw;
  uint32_t off[4];
  float* op[4];
#pragma unroll
  for (int r = 0; r < 4; ++r) {
    off[r] = (uint32_t)sa[r] * ROWB + (uint32_t)cw;
    op[r] = out + (size_t)sa[r] * 256 + jrow0;
  }

  const unsigned char* gig = g_ig;
  uint32_t igA[12], igB[12];
#pragma unroll
  for (int r = 0; r < 4; ++r) {
    igA[r * 3 + 0] = *(const uint32_t*)(gig + off[r]);
    igA[r * 3 + 1] = *(const uint32_t*)(gig + off[r] + 512);
    igA[r * 3 + 2] = *(const uint32_t*)(gig + off[r] + 1024);
    uint32_t nx = off[r] + ROWB; off[r] = nx > offlim ? offlim : nx;
  }
  __syncthreads();

  auto step = [&](int k, uint32_t (&cur)[12], uint32_t (&nxt)[12]) {
#pragma unroll
    for (int r = 0; r < 4; ++r) {
      nxt[r * 3 + 0] = *(const uint32_t*)(gig + off[r]);
      nxt[r * 3 + 1] = *(const uint32_t*)(gig + off[r] + 512);
      nxt[r * 3 + 2] = *(const uint32_t*)(gig + off[r] + 1024);
      uint32_t nx = off[r] + ROWB; off[r] = nx > offlim ? offlim : nx;
    }
    int fnext[4];
    if (k + 1 < 128) {
#pragma unroll
      for (int r = 0; r < 4; ++r) fnext[r] = flg_s[(q * 4 + r) * 132 + k + 1];
    } else {
#pragma unroll
      for (int r = 0; r < 4; ++r) {
        int t = sa[r] + k + 1; t = t > TT - 1 ? TT - 1 : t;
        fnext[r] = start[t];
      }
    }

    const __bf16* hb = &h_s[k & 1][0][0] + l15 * 264 + q * 8;
#pragma unroll
    for (int p = 0; p < 2; ++p) {
      f32x4 a0, a1, a2;
      {
        bf16x8 hf = *(const bf16x8*)(hb);
        i32x4 b0 = *(const i32x4*)(lp + (p * 8) * 1024);
        mfma_bv0(a0, hf, b0);
        mfma_ba0(a1, hf, whh_z[p][0]);
        mfma_ba0(a2, hf, whh_n[p][0]);
      }
#pragma unroll
      for (int ks = 1; ks < 8; ++ks) {
        bf16x8 hf = *(const bf16x8*)(hb + ks * 32);
        i32x4 b0 = *(const i32x4*)(lp + (p * 8 + ks) * 1024);
        mfma_bv(a0, hf, b0);
        mfma_ba(a1, hf, whh_z[p][ks]);
        mfma_ba(a2, hf, whh_n[p][ks]);
      }
      asm volatile("s_nop 7\n\ts_nop 7" : "+v"(a0), "+v"(a1), "+v"(a2));
#pragma unroll
      for (int r = 0; r < 4; ++r) {
        uint32_t vr = cur[r * 3 + 0];
        uint32_t vz = cur[r * 3 + 1];
        uint32_t vn = cur[r * 3 + 2];
        float igr = bfbits(p ? (vr & 0xffff0000u) : (vr << 16));
        float igz = bfbits(p ? (vz & 0xffff0000u) : (vz << 16));
        float ign = bfbits(p ? (vn & 0xffff0000u) : (vn << 16));
        float rp_ = a0[r] + igr;
        float zp_ = a1[r] + igz;
        float hv  = a2[r] + bn2[p];
        float rg = 1.f / (1.f + __expf(-rp_));
        float zg = 1.f / (1.f + __expf(-zp_));
        float np = ign + rg * hv;
        np = fminf(fmaxf(np, -30.f), 30.f);
        float e2 = __expf(2.f * np);
        float ng = (e2 - 1.f) / (e2 + 1.f);
        float hn = ng + zg * (hreg[p][r] - ng);
        if (k < len[r]) {
          __builtin_nontemporal_store(hn, &op[r][p * 16]);
          if (sa[r] + k == TT - 1)   // fin_copy fold: duplicate last row as state
            __builtin_nontemporal_store(hn, out + (size_t)TT * 256 + jrow0 + p * 16);
        }
        hreg[p][r] = fnext[r] ? 0.f : hn;
      }
    }
    __bf16* hw = &h_s[(k + 1) & 1][0][0];
#pragma unroll
    for (int p = 0; p < 2; ++p)
#pragma unroll
      for (int r = 0; r < 4; ++r)
        hw[(q * 4 + r) * 264 + jrow0 + p * 16] = (__bf16)hreg[p][r];
#pragma unroll
    for (int r = 0; r < 4; ++r) op[r] += 256;
    asm volatile("s_waitcnt lgkmcnt(0)" ::: "memory");
    __builtin_amdgcn_s_barrier();
  };

  for (int k = 0; k < ML; ) {
    step(k, igA, igB); ++k;
    if (k < ML) { step(k, igB, igA); ++k; }
  }
}

extern "C" void kernel_launch(void* const* d_in, const int* in_sizes, int n_in,
                              void* d_out, int out_size, void* d_ws, size_t ws_size,
                              hipStream_t stream) {
  const float* x      = (const float*)d_in[0];
  const float* state  = (const float*)d_in[1];
  const int*   start  = (const int*)d_in[2];
  const float* wih    = (const float*)d_in[4];
  const float* whh    = (const float*)d_in[5];
  const float* bias   = (const float*)d_in[6];
  const float* bias_n = (const float*)d_in[7];
  float* out = (float*)d_out;

  gemm_ig<<<1024, 256, 0, stream>>>(x, wih, whh, bias);
  gru_scan<<<NBLK, 512, 0, stream>>>(state, start, bias_n, out);
}

// Round 8
// 251.976 us; speedup vs baseline: 1.1285x; 1.1285x over previous
//
#include <hip/hip_runtime.h>
#include <hip/hip_bf16.h>
#include <stdint.h>

#define TT   65536
#define NCH  16
#define CNOM 16
#define NBLK 256
#define ROWB 1664            // bytes per packed igate row (6*256 used + 128 pad)

typedef __bf16 bf16x8 __attribute__((ext_vector_type(8)));
typedef float  f32x4  __attribute__((ext_vector_type(4)));
typedef int    i32x4  __attribute__((ext_vector_type(4)));

__device__ __bf16 g_whh[768 * 256];
__device__ __align__(64) unsigned char g_ig[(size_t)TT * ROWB];

__device__ __forceinline__ float bfbits(uint32_t u) {
  float f; __builtin_memcpy(&f, &u, 4); return f;
}

// asm MFMA wrappers (scan only). *_0: inline-constant-0 srcC, "=&v" early-clobber.
__device__ __forceinline__ void mfma_bv0(f32x4& acc, bf16x8 a, i32x4 b) {
  asm("v_mfma_f32_16x16x32_bf16 %0, %1, %2, 0" : "=&v"(acc) : "v"(a), "v"(b));
}
__device__ __forceinline__ void mfma_ba0(f32x4& acc, bf16x8 a, i32x4 b) {
  asm("v_mfma_f32_16x16x32_bf16 %0, %1, %2, 0" : "=&v"(acc) : "v"(a), "a"(b));
}
__device__ __forceinline__ void mfma_bv(f32x4& acc, bf16x8 a, i32x4 b) {
  asm("v_mfma_f32_16x16x32_bf16 %0, %1, %2, %0" : "+v"(acc) : "v"(a), "v"(b));
}
__device__ __forceinline__ void mfma_ba(f32x4& acc, bf16x8 a, i32x4 b) {
  asm("v_mfma_f32_16x16x32_bf16 %0, %1, %2, %0" : "+v"(acc) : "v"(a), "a"(b));
}

__device__ __forceinline__ bf16x8 cvt8v(f32x4 f0, f32x4 f1) {
  bf16x8 v;
  v[0] = (__bf16)f0[0]; v[1] = (__bf16)f0[1]; v[2] = (__bf16)f0[2]; v[3] = (__bf16)f0[3];
  v[4] = (__bf16)f1[0]; v[5] = (__bf16)f1[1]; v[6] = (__bf16)f1[2]; v[7] = (__bf16)f1[3];
  return v;
}

// phase 1: igates = x @ W_ih^T + bias -> packed rows; whh->bf16 folded in.
// 1024 blocks x 256 thr: 64-row m-tile, 6 n-tiles in-block, 64 KB LDS ->
// TWO blocks/CU (latency overlap). x loads nontemporal (read-once).
// UNCHANGED from R7 (it improved ~12 us).
__global__ __launch_bounds__(256) void gemm_ig(const float* __restrict__ x,
                                               const float* __restrict__ wih,
                                               const float* __restrict__ whh,
                                               const float* __restrict__ bias) {
  __shared__ __align__(16) __bf16 a_s[4][64 * 64];    // 32 KB: x tile, kc-chunked
  __shared__ __align__(16) __bf16 b_s[2][128 * 64];   // 32 KB: W panel dbuf
  const int tid = threadIdx.x;
  const int lane = tid & 63, l15 = lane & 15, q = lane >> 4;
  const int w = tid >> 6;                             // wave = 32 cols per ntb
  const int m0 = blockIdx.x * 64;

  // prep_w fold: blocks 0..767 convert whh (768*256 elems, 1/thread)
  {
    int i = blockIdx.x * 256 + tid;
    if (i < 768 * 256) g_whh[i] = (__bf16)whh[i];
  }

  float bvA[6], bvB[6];
#pragma unroll
  for (int nb = 0; nb < 6; ++nb) {
    bvA[nb] = bias[nb * 128 + w * 32 + l15];
    bvB[nb] = bias[nb * 128 + w * 32 + 16 + l15];
  }

  // stage x once: LDS[row][c] = global chunk c^(row&7) (write-side swizzle)
#pragma unroll
  for (int kc = 0; kc < 4; ++kc)
#pragma unroll
    for (int i = 0; i < 2; ++i) {
      int pslot = i * 256 + tid;
      int row = pslot >> 3, c = pslot & 7, cs = c ^ (row & 7);
      const f32x4* xs = (const f32x4*)(x + (size_t)(m0 + row) * 256 + kc * 64 + cs * 8);
      f32x4 f0 = __builtin_nontemporal_load(xs);
      f32x4 f1 = __builtin_nontemporal_load(xs + 1);
      *(bf16x8*)((char*)a_s[kc] + pslot * 16) = cvt8v(f0, f1);
    }
  // prologue: W(ntb=0,kc=0) -> b_s[0]
#pragma unroll
  for (int it = 0; it < 4; ++it) {
    int pslot = it * 256 + tid;
    int row = pslot >> 3, c = pslot & 7, cs = c ^ (row & 7);
    const f32x4* ws = (const f32x4*)(wih + (size_t)row * 256 + cs * 8);
    *(bf16x8*)((char*)b_s[0] + pslot * 16) = cvt8v(ws[0], ws[1]);
  }

  f32x4 acc[4][2];
#pragma unroll
  for (int a = 0; a < 4; ++a)
#pragma unroll
    for (int b = 0; b < 2; ++b) acc[a][b] = (f32x4){0.f, 0.f, 0.f, 0.f};
  __syncthreads();

  for (int ci = 0; ci < 24; ++ci) {
    const int ntb = ci >> 2, kc = ci & 3, buf = ci & 1;
    const int nn = (ci + 1) >> 2, kk = (ci + 1) & 3;
    const bool more = (ci + 1) < 24;
    f32x4 wf0[4], wf1[4];
    if (more) {   // issue next W panel loads early (hidden under MFMA + 2nd block)
#pragma unroll
      for (int it = 0; it < 4; ++it) {
        int pslot = it * 256 + tid;
        int row = pslot >> 3, c = pslot & 7, cs = c ^ (row & 7);
        const f32x4* ws = (const f32x4*)(wih + (size_t)(nn * 128 + row) * 256 + kk * 64 + cs * 8);
        wf0[it] = ws[0]; wf1[it] = ws[1];
      }
    }
#pragma unroll
    for (int ks = 0; ks < 2; ++ks) {
      bf16x8 af[4], bfr[2];
#pragma unroll
      for (int tm = 0; tm < 4; ++tm) {
        int row = tm * 16 + l15;
        int cb = (ks * 4 + q) ^ (row & 7);
        af[tm] = *(const bf16x8*)((const char*)a_s[kc] + row * 128 + cb * 16);
      }
#pragma unroll
      for (int tn = 0; tn < 2; ++tn) {
        int row = w * 32 + tn * 16 + l15;
        int cb = (ks * 4 + q) ^ (row & 7);
        bfr[tn] = *(const bf16x8*)((const char*)b_s[buf] + row * 128 + cb * 16);
      }
#pragma unroll
      for (int tm = 0; tm < 4; ++tm)
#pragma unroll
        for (int tn = 0; tn < 2; ++tn)
          acc[tm][tn] = __builtin_amdgcn_mfma_f32_16x16x32_bf16(af[tm], bfr[tn], acc[tm][tn], 0, 0, 0);
    }
    if (more) {   // write next W panel into the idle buffer
#pragma unroll
      for (int it = 0; it < 4; ++it)
        *(bf16x8*)((char*)b_s[buf ^ 1] + (it * 256 + tid) * 16) = cvt8v(wf0[it], wf1[it]);
    }
    if (kc == 3) {
#pragma unroll
      for (int tm = 0; tm < 4; ++tm)
#pragma unroll
        for (int r = 0; r < 4; ++r) {
          int t = m0 + tm * 16 + q * 4 + r;
          __bf16 lo = (__bf16)(acc[tm][0][r] + bvA[ntb]);
          __bf16 hi = (__bf16)(acc[tm][1][r] + bvB[ntb]);
          unsigned short ulo, uhi;
          __builtin_memcpy(&ulo, &lo, 2); __builtin_memcpy(&uhi, &hi, 2);
          uint32_t u = (uint32_t)ulo | ((uint32_t)uhi << 16);
          *(uint32_t*)(g_ig + (size_t)t * ROWB + ntb * 256 + w * 64 + l15 * 4) = u;
        }
#pragma unroll
      for (int a = 0; a < 4; ++a)
#pragma unroll
        for (int b = 0; b < 2; ++b) acc[a][b] = (f32x4){0.f, 0.f, 0.f, 0.f};
    }
    __syncthreads();
  }
}

// phase 2: the scan. vs R7: (a) out stores back to PLAIN stores (nt scattered
// 4B stores defeated L2 write-combining: +13.6 MB WRITE, +5 MB RMW FETCH,
// +14 us); (b) the 3 precise divisions per (p,r) (no fast-math: ~11 instr
// each, ~240 VALU/thread/step) replaced with v_rcp_f32 (1 ulp, fine vs bf16
// threshold). Structure otherwise unchanged.
__global__ __launch_bounds__(512)
__attribute__((amdgpu_waves_per_eu(2, 2)))
void gru_scan(const float* __restrict__ state, const int* __restrict__ start,
              const float* __restrict__ bias_n, float* __restrict__ out) {
  __shared__ __align__(16) __bf16 h_s[2][16][264];
  __shared__ __align__(16) unsigned char whh_lds[8 * 16 * 1024];
  __shared__ int flg_s[16 * 132];
  __shared__ int s_arr[17];

  const int tid = threadIdx.x;
  const int w = tid >> 6, lane = tid & 63, l15 = lane & 15, q = lane >> 4;
  const int jrow0 = w * 32 + l15;

  if (tid < 17) {
    int t = (blockIdx.x * NCH + tid) * CNOM;
    if (t > 0) { while (t < TT && start[t] == 0) t++; }
    s_arr[tid] = t;
  }
  for (int i = tid; i < 16 * 264; i += 512) (&h_s[0][0][0])[i] = (__bf16)0.f;
  __syncthreads();

  int sa[4], len[4];
#pragma unroll
  for (int r = 0; r < 4; ++r) {
    sa[r] = s_arr[q * 4 + r];
    len[r] = s_arr[q * 4 + r + 1] - sa[r];
  }
  int ML = 0;
  for (int m = 0; m < 16; ++m) { int L = s_arr[m + 1] - s_arr[m]; ML = L > ML ? L : ML; }
  ML = __builtin_amdgcn_readfirstlane(ML);

  for (int idx = tid; idx < 2048; idx += 512) {
    int m = idx >> 7, kk = idx & 127;
    int t = s_arr[m] + kk;
    flg_s[m * 132 + kk] = (t < TT) ? start[t] : 0;
  }

  // W_hh c=0 (r-gate) -> per-wave LDS
  char* lp = (char*)whh_lds + w * 16384 + lane * 16;
#pragma unroll
  for (int p = 0; p < 2; ++p)
#pragma unroll
    for (int ks = 0; ks < 8; ++ks) {
      i32x4 t = *(const i32x4*)&g_whh[(size_t)(w * 32 + p * 16 + l15) * 256 + q * 8 + ks * 32];
      *(i32x4*)(lp + (p * 8 + ks) * 1024) = t;
    }
  // W_hh c=1 (z), c=2 (n) -> AGPRs
  i32x4 whh_z[2][8], whh_n[2][8];
#pragma unroll
  for (int p = 0; p < 2; ++p)
#pragma unroll
    for (int ks = 0; ks < 8; ++ks) {
      whh_z[p][ks] = *(const i32x4*)&g_whh[(size_t)(1 * 256 + w * 32 + p * 16 + l15) * 256 + q * 8 + ks * 32];
      whh_n[p][ks] = *(const i32x4*)&g_whh[(size_t)(2 * 256 + w * 32 + p * 16 + l15) * 256 + q * 8 + ks * 32];
    }
#pragma unroll
  for (int p = 0; p < 2; ++p)
#pragma unroll
    for (int ks = 0; ks < 8; ++ks) {
      asm volatile("" : "+a"(whh_z[p][ks]));
      asm volatile("" : "+a"(whh_n[p][ks]));
    }

  const float bn2[2] = { bias_n[jrow0], bias_n[jrow0 + 16] };

  const int start0 = start[0];
  if (blockIdx.x == 0 && tid < 256) h_s[0][0][tid] = start0 ? (__bf16)0.f : (__bf16)state[tid];

  float hreg[2][4];
#pragma unroll
  for (int p = 0; p < 2; ++p)
#pragma unroll
    for (int r = 0; r < 4; ++r) hreg[p][r] = 0.f;
  if (blockIdx.x == 0 && q == 0 && !start0) {
    hreg[0][0] = state[jrow0];
    hreg[1][0] = state[jrow0 + 16];
  }

  const int cw = (w >> 2) * 256 + ((w & 3) * 16 + l15) * 4;
  const uint32_t offlim = (uint32_t)(TT - 1) * ROWB + (uint32_t)cw;
  uint32_t off[4];
  float* op[4];
#pragma unroll
  for (int r = 0; r < 4; ++r) {
    off[r] = (uint32_t)sa[r] * ROWB + (uint32_t)cw;
    op[r] = out + (size_t)sa[r] * 256 + jrow0;
  }

  const unsigned char* gig = g_ig;
  uint32_t igA[12], igB[12];
#pragma unroll
  for (int r = 0; r < 4; ++r) {
    igA[r * 3 + 0] = *(const uint32_t*)(gig + off[r]);
    igA[r * 3 + 1] = *(const uint32_t*)(gig + off[r] + 512);
    igA[r * 3 + 2] = *(const uint32_t*)(gig + off[r] + 1024);
    uint32_t nx = off[r] + ROWB; off[r] = nx > offlim ? offlim : nx;
  }
  __syncthreads();

  auto step = [&](int k, uint32_t (&cur)[12], uint32_t (&nxt)[12]) {
#pragma unroll
    for (int r = 0; r < 4; ++r) {
      nxt[r * 3 + 0] = *(const uint32_t*)(gig + off[r]);
      nxt[r * 3 + 1] = *(const uint32_t*)(gig + off[r] + 512);
      nxt[r * 3 + 2] = *(const uint32_t*)(gig + off[r] + 1024);
      uint32_t nx = off[r] + ROWB; off[r] = nx > offlim ? offlim : nx;
    }
    int fnext[4];
    if (k + 1 < 128) {
#pragma unroll
      for (int r = 0; r < 4; ++r) fnext[r] = flg_s[(q * 4 + r) * 132 + k + 1];
    } else {
#pragma unroll
      for (int r = 0; r < 4; ++r) {
        int t = sa[r] + k + 1; t = t > TT - 1 ? TT - 1 : t;
        fnext[r] = start[t];
      }
    }

    const __bf16* hb = &h_s[k & 1][0][0] + l15 * 264 + q * 8;
#pragma unroll
    for (int p = 0; p < 2; ++p) {
      f32x4 a0, a1, a2;
      {
        bf16x8 hf = *(const bf16x8*)(hb);
        i32x4 b0 = *(const i32x4*)(lp + (p * 8) * 1024);
        mfma_bv0(a0, hf, b0);
        mfma_ba0(a1, hf, whh_z[p][0]);
        mfma_ba0(a2, hf, whh_n[p][0]);
      }
#pragma unroll
      for (int ks = 1; ks < 8; ++ks) {
        bf16x8 hf = *(const bf16x8*)(hb + ks * 32);
        i32x4 b0 = *(const i32x4*)(lp + (p * 8 + ks) * 1024);
        mfma_bv(a0, hf, b0);
        mfma_ba(a1, hf, whh_z[p][ks]);
        mfma_ba(a2, hf, whh_n[p][ks]);
      }
      asm volatile("s_nop 7\n\ts_nop 7" : "+v"(a0), "+v"(a1), "+v"(a2));
#pragma unroll
      for (int r = 0; r < 4; ++r) {
        uint32_t vr = cur[r * 3 + 0];
        uint32_t vz = cur[r * 3 + 1];
        uint32_t vn = cur[r * 3 + 2];
        float igr = bfbits(p ? (vr & 0xffff0000u) : (vr << 16));
        float igz = bfbits(p ? (vz & 0xffff0000u) : (vz << 16));
        float ign = bfbits(p ? (vn & 0xffff0000u) : (vn << 16));
        float rp_ = a0[r] + igr;
        float zp_ = a1[r] + igz;
        float hv  = a2[r] + bn2[p];
        // v_rcp_f32 instead of precise division (no fast-math at -O3):
        // saves ~11 VALU instr per division, 3 divisions per (p,r).
        float rg = __builtin_amdgcn_rcpf(1.f + __expf(-rp_));
        float zg = __builtin_amdgcn_rcpf(1.f + __expf(-zp_));
        float np = ign + rg * hv;
        np = fminf(fmaxf(np, -30.f), 30.f);
        float e2 = __expf(2.f * np);
        float ng = (e2 - 1.f) * __builtin_amdgcn_rcpf(e2 + 1.f);
        float hn = ng + zg * (hreg[p][r] - ng);
        if (k < len[r]) {
          op[r][p * 16] = hn;
          if (sa[r] + k == TT - 1)   // fin_copy fold: duplicate last row as state
            out[(size_t)TT * 256 + jrow0 + p * 16] = hn;
        }
        hreg[p][r] = fnext[r] ? 0.f : hn;
      }
    }
    __bf16* hw = &h_s[(k + 1) & 1][0][0];
#pragma unroll
    for (int p = 0; p < 2; ++p)
#pragma unroll
      for (int r = 0; r < 4; ++r)
        hw[(q * 4 + r) * 264 + jrow0 + p * 16] = (__bf16)hreg[p][r];
#pragma unroll
    for (int r = 0; r < 4; ++r) op[r] += 256;
    asm volatile("s_waitcnt lgkmcnt(0)" ::: "memory");
    __builtin_amdgcn_s_barrier();
  };

  for (int k = 0; k < ML; ) {
    step(k, igA, igB); ++k;
    if (k < ML) { step(k, igB, igA); ++k; }
  }
}

extern "C" void kernel_launch(void* const* d_in, const int* in_sizes, int n_in,
                              void* d_out, int out_size, void* d_ws, size_t ws_size,
                              hipStream_t stream) {
  const float* x      = (const float*)d_in[0];
  const float* state  = (const float*)d_in[1];
  const int*   start  = (const int*)d_in[2];
  const float* wih    = (const float*)d_in[4];
  const float* whh    = (const float*)d_in[5];
  const float* bias   = (const float*)d_in[6];
  const float* bias_n = (const float*)d_in[7];
  float* out = (float*)d_out;

  gemm_ig<<<1024, 256, 0, stream>>>(x, wih, whh, bias);
  gru_scan<<<NBLK, 512, 0, stream>>>(state, start, bias_n, out);
}